// Round 1
// baseline (1131.680 us; speedup 1.0000x reference)
//
#include <hip/hip_runtime.h>
#include <math.h>

#define NF 128
#define EPS 1e-5f
#define BNB 1e-4f

static inline int cdiv(int a, int b){ return (a + b - 1) / b; }

__device__ __forceinline__ float lrelu(float x){ return x > 0.f ? x : 0.2f * x; }
__device__ __forceinline__ float sel4(float4 v, int h){
  float r = v.x;
  r = (h == 1) ? v.y : r;
  r = (h == 2) ? v.z : r;
  r = (h == 3) ? v.w : r;
  return r;
}

// ---------------- CSR build ----------------
__global__ void k_init(int* deg, float* stats, int n, int statcount){
  int i = blockIdx.x * blockDim.x + threadIdx.x;
  if (i < n) deg[i] = 1;                // self-loop contributes 1
  if (i < statcount) stats[i] = 0.f;
}

__global__ void k_hist(const int* __restrict__ ei, int E, int* __restrict__ deg){
  int e = blockIdx.x * blockDim.x + threadIdx.x;
  if (e < E) atomicAdd(&deg[ei[E + e]], 1);
}

// single-block exclusive scan over deg -> off, cursor; off[n] = total
__global__ __launch_bounds__(1024) void k_scan(const int* __restrict__ deg, int* __restrict__ off,
                                               int* __restrict__ cursor, int n){
  const int T = 1024;
  int t = threadIdx.x;
  int per = (n + T - 1) / T;
  int begin = t * per;
  int end = min(begin + per, n);
  int s = 0;
  for (int i = begin; i < end; ++i) s += deg[i];
  int lane = t & 63, w = t >> 6;
  int x = s;
  for (int d = 1; d < 64; d <<= 1){
    int y = __shfl_up(x, d, 64);
    if (lane >= d) x += y;
  }
  __shared__ int wt[16], wex[16];
  if (lane == 63) wt[w] = x;
  __syncthreads();
  if (t < 16){
    int v = wt[t];
    int xx = v;
    for (int d = 1; d < 16; d <<= 1){
      int y = __shfl_up(xx, d, 16);
      if (t >= d) xx += y;
    }
    wex[t] = xx - v;   // exclusive prefix of wave totals
  }
  __syncthreads();
  int run = wex[w] + (x - s);
  for (int i = begin; i < end; ++i){
    off[i] = run; cursor[i] = run;
    run += deg[i];
  }
  if (t == T - 1) off[n] = run;  // last thread's chunk is empty or ends at n -> grand total
}

__global__ void k_scatter(const int* __restrict__ ei, int E, int n,
                          int* __restrict__ cursor, int* __restrict__ esrc){
  int i = blockIdx.x * blockDim.x + threadIdx.x;
  int total = E + n;
  if (i >= total) return;
  int s, d;
  if (i < E){ s = ei[i]; d = ei[E + i]; }
  else { s = i - E; d = s; }
  int pos = atomicAdd(&cursor[d], 1);
  esrc[pos] = s;
}

// ---------------- BN column stats (sum, sumsq into stats[0..127], stats[128..255]) ----------------
__global__ __launch_bounds__(256) void k_colstats(const float* __restrict__ X, int n, float* __restrict__ out){
  __shared__ float ss[4][128], sq[4][128];
  int t = threadIdx.x, lane = t & 63, w = t >> 6;
  float sx = 0.f, sy = 0.f, qx = 0.f, qy = 0.f;
  for (int r = blockIdx.x * 4 + w; r < n; r += gridDim.x * 4){
    float2 v = *(const float2*)(X + (size_t)r * NF + lane * 2);
    sx += v.x; sy += v.y; qx += v.x * v.x; qy += v.y * v.y;
  }
  ss[w][lane * 2] = sx; ss[w][lane * 2 + 1] = sy;
  sq[w][lane * 2] = qx; sq[w][lane * 2 + 1] = qy;
  __syncthreads();
  if (t < 128){
    float tot = ss[0][t] + ss[1][t] + ss[2][t] + ss[3][t];
    atomicAdd(&out[t], tot);
  } else {
    int c = t - 128;
    float tot = sq[0][c] + sq[1][c] + sq[2][c] + sq[3][c];
    atomicAdd(&out[128 + c], tot);
  }
}

// H = (X - m) * rsqrt(var+eps) + BNB
__global__ void k_bnx(const float* __restrict__ X, const float* __restrict__ stats,
                      float* __restrict__ H, int n){
  size_t tot4 = (size_t)n * (NF / 4);
  float inv_n = 1.f / (float)n;
  for (size_t i = blockIdx.x * (size_t)blockDim.x + threadIdx.x; i < tot4;
       i += (size_t)gridDim.x * blockDim.x){
    float4 v = ((const float4*)X)[i];
    int c0 = (int)((i * 4) % NF);
    float* vv = (float*)&v;
    #pragma unroll
    for (int j = 0; j < 4; ++j){
      float m = stats[c0 + j] * inv_n;
      float var = stats[128 + c0 + j] * inv_n - m * m;
      vv[j] = (vv[j] - m) * rsqrtf(var + EPS) + BNB;
    }
    ((float4*)H)[i] = v;
  }
}

// H = relu( (Xg - m)*inv + BNB + H )
__global__ void k_bnres(const float* __restrict__ Xg, const float* __restrict__ stats,
                        float* __restrict__ H, int n){
  size_t tot4 = (size_t)n * (NF / 4);
  float inv_n = 1.f / (float)n;
  for (size_t i = blockIdx.x * (size_t)blockDim.x + threadIdx.x; i < tot4;
       i += (size_t)gridDim.x * blockDim.x){
    float4 v = ((const float4*)Xg)[i];
    float4 hc = ((const float4*)H)[i];
    int c0 = (int)((i * 4) % NF);
    float* vv = (float*)&v;
    float* hh = (float*)&hc;
    #pragma unroll
    for (int j = 0; j < 4; ++j){
      float m = stats[c0 + j] * inv_n;
      float var = stats[128 + c0 + j] * inv_n - m * m;
      float z = (vv[j] - m) * rsqrtf(var + EPS) + BNB + hh[j];
      hh[j] = fmaxf(z, 0.f);
    }
    ((float4*)H)[i] = hc;
  }
}

__global__ void k_relu(const float* __restrict__ X, float* __restrict__ H, size_t tot4){
  for (size_t i = blockIdx.x * (size_t)blockDim.x + threadIdx.x; i < tot4;
       i += (size_t)gridDim.x * blockDim.x){
    float4 v = ((const float4*)X)[i];
    v.x = fmaxf(v.x, 0.f); v.y = fmaxf(v.y, 0.f);
    v.z = fmaxf(v.z, 0.f); v.w = fmaxf(v.w, 0.f);
    ((float4*)H)[i] = v;
  }
}

// ---------------- GEMM: Y[n,128] = X[n,128] @ W[128,128] ----------------
__global__ __launch_bounds__(256) void k_gemm(const float* __restrict__ X, const float* __restrict__ W,
                                              float* __restrict__ Y, int n){
  __shared__ float sW[128 * 128];
  __shared__ float sX[32 * 128];
  int t = threadIdx.x;
  #pragma unroll
  for (int i = 0; i < 16; ++i){
    int i4 = t + 256 * i;
    ((float4*)sW)[i4] = ((const float4*)W)[i4];
  }
  int rbase = blockIdx.x * 32;
  #pragma unroll
  for (int i = 0; i < 4; ++i){
    int i4 = t + 256 * i;
    int row = i4 >> 5, c4 = i4 & 31;
    int gr = rbase + row;
    float4 v = (gr < n) ? ((const float4*)(X + (size_t)gr * NF))[c4] : make_float4(0, 0, 0, 0);
    ((float4*)sX)[i4] = v;
  }
  __syncthreads();
  int c0 = (t & 31) * 4;
  int r0 = (t >> 5) * 4;
  float4 acc[4];
  #pragma unroll
  for (int i = 0; i < 4; ++i) acc[i] = make_float4(0, 0, 0, 0);
  for (int k4 = 0; k4 < 32; ++k4){
    float4 xv[4], wv[4];
    #pragma unroll
    for (int i = 0; i < 4; ++i) xv[i] = *(const float4*)&sX[(r0 + i) * 128 + k4 * 4];
    #pragma unroll
    for (int j = 0; j < 4; ++j) wv[j] = *(const float4*)&sW[(k4 * 4 + j) * 128 + c0];
    #pragma unroll
    for (int i = 0; i < 4; ++i){
      const float* xp = (const float*)&xv[i];
      float* ap = (float*)&acc[i];
      #pragma unroll
      for (int j = 0; j < 4; ++j){
        const float* wp = (const float*)&wv[j];
        float xs = xp[j];
        ap[0] += xs * wp[0]; ap[1] += xs * wp[1];
        ap[2] += xs * wp[2]; ap[3] += xs * wp[3];
      }
    }
  }
  #pragma unroll
  for (int i = 0; i < 4; ++i){
    int gr = rbase + r0 + i;
    if (gr < n) *(float4*)(Y + (size_t)gr * NF + c0) = acc[i];
  }
}

// ---------------- per-node attention coefficients a_s, a_d ----------------
__global__ __launch_bounds__(256) void k_attvec(const float* __restrict__ Hm, const float* __restrict__ asrc,
                                                const float* __restrict__ adst, float* __restrict__ a_s,
                                                float* __restrict__ a_d, int n){
  int t = threadIdx.x, lane = t & 63, w = t >> 6;
  int r = blockIdx.x * 4 + w;
  if (r >= n) return;
  float2 v = *(const float2*)(Hm + (size_t)r * NF + lane * 2);
  float2 us = *(const float2*)(asrc + lane * 2);
  float2 ud = *(const float2*)(adst + lane * 2);
  float ps = v.x * us.x + v.y * us.y;
  float pd = v.x * ud.x + v.y * ud.y;
  #pragma unroll
  for (int d = 1; d < 16; d <<= 1){
    ps += __shfl_xor(ps, d, 64);
    pd += __shfl_xor(pd, d, 64);
  }
  if ((lane & 15) == 0){
    int h = lane >> 4;
    a_s[(size_t)r * 4 + h] = ps;
    a_d[(size_t)r * 4 + h] = pd;
  }
}

// ---------------- attention softmax + aggregate, one wave per dst node ----------------
__global__ __launch_bounds__(256) void k_attn(const float* __restrict__ Hm, const float* __restrict__ a_s,
                                              const float* __restrict__ a_d, const int* __restrict__ off,
                                              const int* __restrict__ esrc, const float* __restrict__ bias,
                                              float* __restrict__ Y, int n){
  int t = threadIdx.x, lane = t & 63, w = t >> 6;
  int node = blockIdx.x * 4 + w;
  if (node >= n) return;
  int head = lane >> 4;
  float4 ad4 = ((const float4*)a_d)[node];
  float adh = sel4(ad4, head);
  int lo = off[node], hi = off[node + 1];
  float m = -3.4e38f;
  for (int e = lo; e < hi; ++e){
    int s = esrc[e];
    float ash = sel4(((const float4*)a_s)[s], head);
    m = fmaxf(m, lrelu(ash + adh));
  }
  float sum = 0.f;
  float ax = 0.f, ay = 0.f;
  for (int e = lo; e < hi; ++e){
    int s = esrc[e];
    float ash = sel4(((const float4*)a_s)[s], head);
    float wgt = __expf(lrelu(ash + adh) - m);
    sum += wgt;
    float2 hv = *(const float2*)(Hm + (size_t)s * NF + lane * 2);
    ax += hv.x * wgt; ay += hv.y * wgt;
  }
  float inv = 1.f / (sum + 1e-16f);
  float2 b = *(const float2*)(bias + lane * 2);
  float2 r;
  r.x = ax * inv + b.x;
  r.y = ay * inv + b.y;
  *(float2*)(Y + (size_t)node * NF + lane * 2) = r;
}

// ---------------- pooling: batch is sorted; one block per graph ----------------
__global__ __launch_bounds__(256) void k_pool(const float* __restrict__ H, const int* __restrict__ batch,
                                              float* __restrict__ g, int n){
  int gid = blockIdx.x;
  int t = threadIdx.x, lane = t & 63, w = t >> 6;
  int lo = 0, hi = n;
  while (lo < hi){ int mid = (lo + hi) >> 1; if (batch[mid] < gid) lo = mid + 1; else hi = mid; }
  int a = lo, b = n;
  while (a < b){ int mid = (a + b) >> 1; if (batch[mid] < gid + 1) a = mid + 1; else b = mid; }
  float sx = 0.f, sy = 0.f;
  for (int r = lo + w; r < a; r += 4){
    float2 v = *(const float2*)(H + (size_t)r * NF + lane * 2);
    sx += v.x; sy += v.y;
  }
  __shared__ float ss[4][128];
  ss[w][lane * 2] = sx; ss[w][lane * 2 + 1] = sy;
  __syncthreads();
  if (t < 128) g[(size_t)gid * NF + t] = ss[0][t] + ss[1][t] + ss[2][t] + ss[3][t];
}

// ---------------- head: BN -> fc+relu -> BN -> cls -> log_softmax (single block) ----------------
__global__ __launch_bounds__(1024) void k_head(const float* __restrict__ g, const float* __restrict__ fc_w,
                                               const float* __restrict__ fc_b, const float* __restrict__ cls_w,
                                               const float* __restrict__ cls_b, float* __restrict__ out){
  __shared__ float A[128 * 128];
  __shared__ float mbuf[128], ibuf[128];
  __shared__ float logits[256];
  int t = threadIdx.x;
  #pragma unroll
  for (int i = 0; i < 4; ++i)
    ((float4*)A)[t + 1024 * i] = ((const float4*)g)[t + 1024 * i];
  __syncthreads();
  // BN1 stats over 128 rows
  if (t < 128){
    float s = 0.f, q = 0.f;
    for (int r = 0; r < 128; ++r){ float v = A[r * 128 + t]; s += v; q += v * v; }
    float m = s * (1.f / 128.f);
    float var = q * (1.f / 128.f) - m * m;
    mbuf[t] = m; ibuf[t] = rsqrtf(var + EPS);
  }
  __syncthreads();
  #pragma unroll
  for (int i = 0; i < 16; ++i){
    int idx = t + 1024 * i;
    int c = idx & 127;
    A[idx] = (A[idx] - mbuf[c]) * ibuf[c] + BNB;
  }
  __syncthreads();
  // fc: each thread computes rows r0..r0+3 x cols c0..c0+3
  int c0 = (t & 31) * 4, r0 = (t >> 5) * 4;
  float o[4][4];
  float4 bb = *(const float4*)(fc_b + c0);
  #pragma unroll
  for (int i = 0; i < 4; ++i){ o[i][0] = bb.x; o[i][1] = bb.y; o[i][2] = bb.z; o[i][3] = bb.w; }
  for (int k = 0; k < 128; ++k){
    float4 wv = *(const float4*)(fc_w + (size_t)k * 128 + c0);
    #pragma unroll
    for (int i = 0; i < 4; ++i){
      float xs = A[(r0 + i) * 128 + k];
      o[i][0] += xs * wv.x; o[i][1] += xs * wv.y;
      o[i][2] += xs * wv.z; o[i][3] += xs * wv.w;
    }
  }
  __syncthreads();
  #pragma unroll
  for (int i = 0; i < 4; ++i)
    #pragma unroll
    for (int j = 0; j < 4; ++j)
      A[(r0 + i) * 128 + c0 + j] = fmaxf(o[i][j], 0.f);
  __syncthreads();
  // BN2
  if (t < 128){
    float s = 0.f, q = 0.f;
    for (int r = 0; r < 128; ++r){ float v = A[r * 128 + t]; s += v; q += v * v; }
    float m = s * (1.f / 128.f);
    float var = q * (1.f / 128.f) - m * m;
    mbuf[t] = m; ibuf[t] = rsqrtf(var + EPS);
  }
  __syncthreads();
  #pragma unroll
  for (int i = 0; i < 16; ++i){
    int idx = t + 1024 * i;
    int c = idx & 127;
    A[idx] = (A[idx] - mbuf[c]) * ibuf[c] + BNB;
  }
  __syncthreads();
  // classifier + log_softmax
  if (t < 256){
    int r = t >> 1, j = t & 1;
    float accv = cls_b[j];
    for (int k = 0; k < 128; ++k) accv += A[r * 128 + k] * cls_w[k * 2 + j];
    logits[t] = accv;
  }
  __syncthreads();
  if (t < 256){
    int r = t >> 1;
    float l0 = logits[r * 2], l1 = logits[r * 2 + 1];
    float mx = fmaxf(l0, l1);
    float lse = mx + logf(__expf(l0 - mx) + __expf(l1 - mx));
    out[t] = logits[t] - lse;
  }
}

extern "C" void kernel_launch(void* const* d_in, const int* in_sizes, int n_in,
                              void* d_out, int out_size, void* d_ws, size_t ws_size,
                              hipStream_t stream){
  const float* x        = (const float*)d_in[0];
  const int*   ei       = (const int*)d_in[1];
  const int*   batch    = (const int*)d_in[2];
  const float* gat_lin  = (const float*)d_in[3];
  const float* att_src  = (const float*)d_in[4];
  const float* att_dst  = (const float*)d_in[5];
  const float* gat_bias = (const float*)d_in[6];
  const float* fc_w     = (const float*)d_in[7];
  const float* fc_b     = (const float*)d_in[8];
  const float* cls_w    = (const float*)d_in[9];
  const float* cls_b    = (const float*)d_in[10];
  float* out = (float*)d_out;
  (void)n_in; (void)out_size; (void)ws_size;

  int N = in_sizes[0] / NF;
  int E = in_sizes[1] / 2;

  char* p = (char*)d_ws;
  auto alloc = [&](size_t bytes) -> char* {
    char* r = p;
    p += (bytes + 255) & ~(size_t)255;
    return r;
  };
  int*   deg    = (int*)alloc((size_t)N * 4);
  int*   off    = (int*)alloc((size_t)(N + 1) * 4);
  int*   cursor = (int*)alloc((size_t)N * 4);
  int*   esrc   = (int*)alloc((size_t)(E + N) * 4);
  float* stats  = (float*)alloc(4 * 256 * 4);
  float* hbuf   = (float*)alloc((size_t)N * NF * 4);
  float* tmp    = (float*)alloc((size_t)N * NF * 4);
  float* gout   = (float*)alloc((size_t)N * NF * 4);
  float* a_s    = (float*)alloc((size_t)N * 4 * 4);
  float* a_d    = (float*)alloc((size_t)N * 4 * 4);
  float* gpool  = (float*)alloc(128 * NF * 4);

  k_init<<<cdiv(N, 256), 256, 0, stream>>>(deg, stats, N, 1024);
  k_hist<<<cdiv(E, 256), 256, 0, stream>>>(ei, E, deg);
  k_scan<<<1, 1024, 0, stream>>>(deg, off, cursor, N);
  k_scatter<<<cdiv(E + N, 256), 256, 0, stream>>>(ei, E, N, cursor, esrc);

  k_colstats<<<256, 256, 0, stream>>>(x, N, stats);
  k_bnx<<<1024, 256, 0, stream>>>(x, stats, hbuf, N);

  for (int L = 0; L < 4; ++L){
    k_gemm<<<cdiv(N, 32), 256, 0, stream>>>(hbuf, gat_lin + (size_t)L * NF * NF, tmp, N);
    k_attvec<<<cdiv(N, 4), 256, 0, stream>>>(tmp, att_src + (size_t)L * NF, att_dst + (size_t)L * NF,
                                             a_s, a_d, N);
    k_attn<<<cdiv(N, 4), 256, 0, stream>>>(tmp, a_s, a_d, off, esrc,
                                           gat_bias + (size_t)L * NF, gout, N);
    if (L == 0){
      k_relu<<<1024, 256, 0, stream>>>(gout, hbuf, (size_t)N * (NF / 4));
    } else {
      k_colstats<<<256, 256, 0, stream>>>(gout, N, stats + L * 256);
      k_bnres<<<1024, 256, 0, stream>>>(gout, stats + L * 256, hbuf, N);
    }
  }

  k_pool<<<128, 256, 0, stream>>>(hbuf, batch, gpool, N);
  k_head<<<1, 1024, 0, stream>>>(gpool, fc_w, fc_b, cls_w, cls_b, out);
}

// Round 2
// 820.236 us; speedup vs baseline: 1.3797x; 1.3797x over previous
//
#include <hip/hip_runtime.h>
#include <math.h>

#define NF 128
#define EPS 1e-5f
#define BNB 1e-4f

static inline int cdiv(int a, int b){ return (a + b - 1) / b; }

__device__ __forceinline__ float lrelu(float x){ return x > 0.f ? x : 0.2f * x; }

// ---------------- CSR build ----------------
__global__ void k_init(int* deg, float* stats, int n, int statcount){
  int i = blockIdx.x * blockDim.x + threadIdx.x;
  if (i < n) deg[i] = 1;                // self-loop contributes 1
  if (i < statcount) stats[i] = 0.f;
}

__global__ void k_hist(const int* __restrict__ ei, int E, int* __restrict__ deg){
  int e = blockIdx.x * blockDim.x + threadIdx.x;
  if (e < E) atomicAdd(&deg[ei[E + e]], 1);
}

// single-block exclusive scan over deg -> off, cursor; off[n] = total
__global__ __launch_bounds__(1024) void k_scan(const int* __restrict__ deg, int* __restrict__ off,
                                               int* __restrict__ cursor, int n){
  const int T = 1024;
  int t = threadIdx.x;
  int per = (n + T - 1) / T;
  int begin = t * per;
  int end = min(begin + per, n);
  int s = 0;
  for (int i = begin; i < end; ++i) s += deg[i];
  int lane = t & 63, w = t >> 6;
  int x = s;
  for (int d = 1; d < 64; d <<= 1){
    int y = __shfl_up(x, d, 64);
    if (lane >= d) x += y;
  }
  __shared__ int wt[16], wex[16];
  if (lane == 63) wt[w] = x;
  __syncthreads();
  if (t < 16){
    int v = wt[t];
    int xx = v;
    for (int d = 1; d < 16; d <<= 1){
      int y = __shfl_up(xx, d, 16);
      if (t >= d) xx += y;
    }
    wex[t] = xx - v;   // exclusive prefix of wave totals
  }
  __syncthreads();
  int run = wex[w] + (x - s);
  for (int i = begin; i < end; ++i){
    off[i] = run; cursor[i] = run;
    run += deg[i];
  }
  if (t == T - 1) off[n] = run;
}

__global__ void k_scatter(const int* __restrict__ ei, int E, int n,
                          int* __restrict__ cursor, int* __restrict__ esrc,
                          int* __restrict__ edst){
  int i = blockIdx.x * blockDim.x + threadIdx.x;
  int total = E + n;
  if (i >= total) return;
  int s, d;
  if (i < E){ s = ei[i]; d = ei[E + i]; }
  else { s = i - E; d = s; }
  int pos = atomicAdd(&cursor[d], 1);
  esrc[pos] = s;
  edst[pos] = d;
}

// ---------------- BN column stats (sum, sumsq into stats[0..127], stats[128..255]) ----------------
__global__ __launch_bounds__(256) void k_colstats(const float* __restrict__ X, int n, float* __restrict__ out){
  __shared__ float ss[4][128], sq[4][128];
  int t = threadIdx.x, lane = t & 63, w = t >> 6;
  float sx = 0.f, sy = 0.f, qx = 0.f, qy = 0.f;
  for (int r = blockIdx.x * 4 + w; r < n; r += gridDim.x * 4){
    float2 v = *(const float2*)(X + (size_t)r * NF + lane * 2);
    sx += v.x; sy += v.y; qx += v.x * v.x; qy += v.y * v.y;
  }
  ss[w][lane * 2] = sx; ss[w][lane * 2 + 1] = sy;
  sq[w][lane * 2] = qx; sq[w][lane * 2 + 1] = qy;
  __syncthreads();
  if (t < 128){
    float tot = ss[0][t] + ss[1][t] + ss[2][t] + ss[3][t];
    atomicAdd(&out[t], tot);
  } else {
    int c = t - 128;
    float tot = sq[0][c] + sq[1][c] + sq[2][c] + sq[3][c];
    atomicAdd(&out[128 + c], tot);
  }
}

// H = (X - m) * rsqrt(var+eps) + BNB
__global__ void k_bnx(const float* __restrict__ X, const float* __restrict__ stats,
                      float* __restrict__ H, int n){
  size_t tot4 = (size_t)n * (NF / 4);
  float inv_n = 1.f / (float)n;
  for (size_t i = blockIdx.x * (size_t)blockDim.x + threadIdx.x; i < tot4;
       i += (size_t)gridDim.x * blockDim.x){
    float4 v = ((const float4*)X)[i];
    int c0 = (int)((i * 4) % NF);
    float* vv = (float*)&v;
    #pragma unroll
    for (int j = 0; j < 4; ++j){
      float m = stats[c0 + j] * inv_n;
      float var = stats[128 + c0 + j] * inv_n - m * m;
      vv[j] = (vv[j] - m) * rsqrtf(var + EPS) + BNB;
    }
    ((float4*)H)[i] = v;
  }
}

// H = relu( (Xg - m)*inv + BNB + H )
__global__ void k_bnres(const float* __restrict__ Xg, const float* __restrict__ stats,
                        float* __restrict__ H, int n){
  size_t tot4 = (size_t)n * (NF / 4);
  float inv_n = 1.f / (float)n;
  for (size_t i = blockIdx.x * (size_t)blockDim.x + threadIdx.x; i < tot4;
       i += (size_t)gridDim.x * blockDim.x){
    float4 v = ((const float4*)Xg)[i];
    float4 hc = ((const float4*)H)[i];
    int c0 = (int)((i * 4) % NF);
    float* vv = (float*)&v;
    float* hh = (float*)&hc;
    #pragma unroll
    for (int j = 0; j < 4; ++j){
      float m = stats[c0 + j] * inv_n;
      float var = stats[128 + c0 + j] * inv_n - m * m;
      float z = (vv[j] - m) * rsqrtf(var + EPS) + BNB + hh[j];
      hh[j] = fmaxf(z, 0.f);
    }
    ((float4*)H)[i] = hc;
  }
}

__global__ void k_relu(const float* __restrict__ X, float* __restrict__ H, size_t tot4){
  for (size_t i = blockIdx.x * (size_t)blockDim.x + threadIdx.x; i < tot4;
       i += (size_t)gridDim.x * blockDim.x){
    float4 v = ((const float4*)X)[i];
    v.x = fmaxf(v.x, 0.f); v.y = fmaxf(v.y, 0.f);
    v.z = fmaxf(v.z, 0.f); v.w = fmaxf(v.w, 0.f);
    ((float4*)H)[i] = v;
  }
}

// ---------------- GEMM: Y[n,128] = X[n,128] @ W[128,128] ----------------
__global__ __launch_bounds__(256) void k_gemm(const float* __restrict__ X, const float* __restrict__ W,
                                              float* __restrict__ Y, int n){
  __shared__ float sW[128 * 128];
  __shared__ float sX[32 * 128];
  int t = threadIdx.x;
  #pragma unroll
  for (int i = 0; i < 16; ++i){
    int i4 = t + 256 * i;
    ((float4*)sW)[i4] = ((const float4*)W)[i4];
  }
  int rbase = blockIdx.x * 32;
  #pragma unroll
  for (int i = 0; i < 4; ++i){
    int i4 = t + 256 * i;
    int row = i4 >> 5, c4 = i4 & 31;
    int gr = rbase + row;
    float4 v = (gr < n) ? ((const float4*)(X + (size_t)gr * NF))[c4] : make_float4(0, 0, 0, 0);
    ((float4*)sX)[i4] = v;
  }
  __syncthreads();
  int c0 = (t & 31) * 4;
  int r0 = (t >> 5) * 4;
  float4 acc[4];
  #pragma unroll
  for (int i = 0; i < 4; ++i) acc[i] = make_float4(0, 0, 0, 0);
  for (int k4 = 0; k4 < 32; ++k4){
    float4 xv[4], wv[4];
    #pragma unroll
    for (int i = 0; i < 4; ++i) xv[i] = *(const float4*)&sX[(r0 + i) * 128 + k4 * 4];
    #pragma unroll
    for (int j = 0; j < 4; ++j) wv[j] = *(const float4*)&sW[(k4 * 4 + j) * 128 + c0];
    #pragma unroll
    for (int i = 0; i < 4; ++i){
      const float* xp = (const float*)&xv[i];
      float* ap = (float*)&acc[i];
      #pragma unroll
      for (int j = 0; j < 4; ++j){
        const float* wp = (const float*)&wv[j];
        float xs = xp[j];
        ap[0] += xs * wp[0]; ap[1] += xs * wp[1];
        ap[2] += xs * wp[2]; ap[3] += xs * wp[3];
      }
    }
  }
  #pragma unroll
  for (int i = 0; i < 4; ++i){
    int gr = rbase + r0 + i;
    if (gr < n) *(float4*)(Y + (size_t)gr * NF + c0) = acc[i];
  }
}

// ---------------- per-node attention coefficients a_s, a_d ----------------
__global__ __launch_bounds__(256) void k_attvec(const float* __restrict__ Hm, const float* __restrict__ asrc,
                                                const float* __restrict__ adst, float* __restrict__ a_s,
                                                float* __restrict__ a_d, int n){
  int t = threadIdx.x, lane = t & 63, w = t >> 6;
  int r = blockIdx.x * 4 + w;
  if (r >= n) return;
  float2 v = *(const float2*)(Hm + (size_t)r * NF + lane * 2);
  float2 us = *(const float2*)(asrc + lane * 2);
  float2 ud = *(const float2*)(adst + lane * 2);
  float ps = v.x * us.x + v.y * us.y;
  float pd = v.x * ud.x + v.y * ud.y;
  #pragma unroll
  for (int d = 1; d < 16; d <<= 1){
    ps += __shfl_xor(ps, d, 64);
    pd += __shfl_xor(pd, d, 64);
  }
  if ((lane & 15) == 0){
    int h = lane >> 4;
    a_s[(size_t)r * 4 + h] = ps;
    a_d[(size_t)r * 4 + h] = pd;
  }
}

// ---------------- per-edge alpha, SoA by head: ealpha[h*total + e] ----------------
__global__ void k_edgealpha(const int* __restrict__ esrc, const int* __restrict__ edst,
                            const float4* __restrict__ a_s, const float4* __restrict__ a_d,
                            float* __restrict__ ealpha, int total){
  int e = blockIdx.x * blockDim.x + threadIdx.x;
  if (e >= total) return;
  float4 as = a_s[esrc[e]];
  float4 ad = a_d[edst[e]];
  ealpha[e]             = lrelu(as.x + ad.x);
  ealpha[total + e]     = lrelu(as.y + ad.y);
  ealpha[2 * total + e] = lrelu(as.z + ad.z);
  ealpha[3 * total + e] = lrelu(as.w + ad.w);
}

// ---------------- attention: single-pass online softmax + aggregate, unroll 4 ----------------
__global__ __launch_bounds__(256) void k_attn(const float* __restrict__ Hm,
                                              const float* __restrict__ ealpha,
                                              const int* __restrict__ off,
                                              const int* __restrict__ esrc,
                                              const float* __restrict__ bias,
                                              float* __restrict__ Y, int n, int estride){
  int t = threadIdx.x, lane = t & 63, w = t >> 6;
  int node = blockIdx.x * 4 + w;
  if (node >= n) return;
  node = __builtin_amdgcn_readfirstlane(node);
  int head = lane >> 4;
  const float* ep = ealpha + (size_t)head * estride;
  int lo = off[node], hi = off[node + 1];
  lo = __builtin_amdgcn_readfirstlane(lo);
  hi = __builtin_amdgcn_readfirstlane(hi);
  int fo = lane * 2;
  float m = -3.4e38f, sum = 0.f, ax = 0.f, ay = 0.f;
  for (int e = lo; e < hi; e += 4){
    int e1 = min(e + 1, hi - 1), e2 = min(e + 2, hi - 1), e3 = min(e + 3, hi - 1);
    int s0 = esrc[e], s1 = esrc[e1], s2 = esrc[e2], s3 = esrc[e3];
    float a0 = ep[e], a1 = ep[e1], a2 = ep[e2], a3 = ep[e3];
    float2 h0 = *(const float2*)(Hm + (size_t)s0 * NF + fo);
    float2 h1 = *(const float2*)(Hm + (size_t)s1 * NF + fo);
    float2 h2 = *(const float2*)(Hm + (size_t)s2 * NF + fo);
    float2 h3 = *(const float2*)(Hm + (size_t)s3 * NF + fo);
    if (e + 1 >= hi) a1 = -3.4e38f;   // clamped duplicates get weight 0
    if (e + 2 >= hi) a2 = -3.4e38f;
    if (e + 3 >= hi) a3 = -3.4e38f;
    float mm = fmaxf(fmaxf(a0, a1), fmaxf(a2, a3));
    float newm = fmaxf(m, mm);
    float c = __expf(m - newm);       // first iter: exp(-inf) = 0, acc was 0 anyway
    float w0 = __expf(a0 - newm), w1 = __expf(a1 - newm);
    float w2 = __expf(a2 - newm), w3 = __expf(a3 - newm);
    sum = sum * c + (w0 + w1 + w2 + w3);
    ax = ax * c + w0 * h0.x + w1 * h1.x + w2 * h2.x + w3 * h3.x;
    ay = ay * c + w0 * h0.y + w1 * h1.y + w2 * h2.y + w3 * h3.y;
    m = newm;
  }
  float inv = 1.f / (sum + 1e-16f);
  float2 b = *(const float2*)(bias + fo);
  float2 r;
  r.x = ax * inv + b.x;
  r.y = ay * inv + b.y;
  *(float2*)(Y + (size_t)node * NF + fo) = r;
}

// ---------------- pooling: batch is sorted; one block per graph ----------------
__global__ __launch_bounds__(256) void k_pool(const float* __restrict__ H, const int* __restrict__ batch,
                                              float* __restrict__ g, int n){
  int gid = blockIdx.x;
  int t = threadIdx.x, lane = t & 63, w = t >> 6;
  int lo = 0, hi = n;
  while (lo < hi){ int mid = (lo + hi) >> 1; if (batch[mid] < gid) lo = mid + 1; else hi = mid; }
  int a = lo, b = n;
  while (a < b){ int mid = (a + b) >> 1; if (batch[mid] < gid + 1) a = mid + 1; else b = mid; }
  float sx = 0.f, sy = 0.f;
  for (int r = lo + w; r < a; r += 4){
    float2 v = *(const float2*)(H + (size_t)r * NF + lane * 2);
    sx += v.x; sy += v.y;
  }
  __shared__ float ss[4][128];
  ss[w][lane * 2] = sx; ss[w][lane * 2 + 1] = sy;
  __syncthreads();
  if (t < 128) g[(size_t)gid * NF + t] = ss[0][t] + ss[1][t] + ss[2][t] + ss[3][t];
}

// ---------------- head: BN -> fc+relu -> BN -> cls -> log_softmax (single block) ----------------
__global__ __launch_bounds__(1024) void k_head(const float* __restrict__ g, const float* __restrict__ fc_w,
                                               const float* __restrict__ fc_b, const float* __restrict__ cls_w,
                                               const float* __restrict__ cls_b, float* __restrict__ out){
  __shared__ float A[128 * 128];
  __shared__ float mbuf[128], ibuf[128];
  __shared__ float logits[256];
  int t = threadIdx.x;
  #pragma unroll
  for (int i = 0; i < 4; ++i)
    ((float4*)A)[t + 1024 * i] = ((const float4*)g)[t + 1024 * i];
  __syncthreads();
  if (t < 128){
    float s = 0.f, q = 0.f;
    for (int r = 0; r < 128; ++r){ float v = A[r * 128 + t]; s += v; q += v * v; }
    float m = s * (1.f / 128.f);
    float var = q * (1.f / 128.f) - m * m;
    mbuf[t] = m; ibuf[t] = rsqrtf(var + EPS);
  }
  __syncthreads();
  #pragma unroll
  for (int i = 0; i < 16; ++i){
    int idx = t + 1024 * i;
    int c = idx & 127;
    A[idx] = (A[idx] - mbuf[c]) * ibuf[c] + BNB;
  }
  __syncthreads();
  int c0 = (t & 31) * 4, r0 = (t >> 5) * 4;
  float o[4][4];
  float4 bb = *(const float4*)(fc_b + c0);
  #pragma unroll
  for (int i = 0; i < 4; ++i){ o[i][0] = bb.x; o[i][1] = bb.y; o[i][2] = bb.z; o[i][3] = bb.w; }
  for (int k = 0; k < 128; ++k){
    float4 wv = *(const float4*)(fc_w + (size_t)k * 128 + c0);
    #pragma unroll
    for (int i = 0; i < 4; ++i){
      float xs = A[(r0 + i) * 128 + k];
      o[i][0] += xs * wv.x; o[i][1] += xs * wv.y;
      o[i][2] += xs * wv.z; o[i][3] += xs * wv.w;
    }
  }
  __syncthreads();
  #pragma unroll
  for (int i = 0; i < 4; ++i)
    #pragma unroll
    for (int j = 0; j < 4; ++j)
      A[(r0 + i) * 128 + c0 + j] = fmaxf(o[i][j], 0.f);
  __syncthreads();
  if (t < 128){
    float s = 0.f, q = 0.f;
    for (int r = 0; r < 128; ++r){ float v = A[r * 128 + t]; s += v; q += v * v; }
    float m = s * (1.f / 128.f);
    float var = q * (1.f / 128.f) - m * m;
    mbuf[t] = m; ibuf[t] = rsqrtf(var + EPS);
  }
  __syncthreads();
  #pragma unroll
  for (int i = 0; i < 16; ++i){
    int idx = t + 1024 * i;
    int c = idx & 127;
    A[idx] = (A[idx] - mbuf[c]) * ibuf[c] + BNB;
  }
  __syncthreads();
  if (t < 256){
    int r = t >> 1, j = t & 1;
    float accv = cls_b[j];
    for (int k = 0; k < 128; ++k) accv += A[r * 128 + k] * cls_w[k * 2 + j];
    logits[t] = accv;
  }
  __syncthreads();
  if (t < 256){
    int r = t >> 1;
    float l0 = logits[r * 2], l1 = logits[r * 2 + 1];
    float mx = fmaxf(l0, l1);
    float lse = mx + logf(__expf(l0 - mx) + __expf(l1 - mx));
    out[t] = logits[t] - lse;
  }
}

extern "C" void kernel_launch(void* const* d_in, const int* in_sizes, int n_in,
                              void* d_out, int out_size, void* d_ws, size_t ws_size,
                              hipStream_t stream){
  const float* x        = (const float*)d_in[0];
  const int*   ei       = (const int*)d_in[1];
  const int*   batch    = (const int*)d_in[2];
  const float* gat_lin  = (const float*)d_in[3];
  const float* att_src  = (const float*)d_in[4];
  const float* att_dst  = (const float*)d_in[5];
  const float* gat_bias = (const float*)d_in[6];
  const float* fc_w     = (const float*)d_in[7];
  const float* fc_b     = (const float*)d_in[8];
  const float* cls_w    = (const float*)d_in[9];
  const float* cls_b    = (const float*)d_in[10];
  float* out = (float*)d_out;
  (void)n_in; (void)out_size; (void)ws_size;

  int N = in_sizes[0] / NF;
  int E = in_sizes[1] / 2;
  int total = E + N;

  char* p = (char*)d_ws;
  auto alloc = [&](size_t bytes) -> char* {
    char* r = p;
    p += (bytes + 255) & ~(size_t)255;
    return r;
  };
  int*   deg    = (int*)alloc((size_t)N * 4);
  int*   off    = (int*)alloc((size_t)(N + 1) * 4);
  int*   cursor = (int*)alloc((size_t)N * 4);
  int*   esrc   = (int*)alloc((size_t)total * 4);
  int*   edst   = (int*)alloc((size_t)total * 4);
  float* ealpha = (float*)alloc((size_t)total * 4 * 4);
  float* stats  = (float*)alloc(4 * 256 * 4);
  float* hbuf   = (float*)alloc((size_t)N * NF * 4);
  float* tmp    = (float*)alloc((size_t)N * NF * 4);
  float* gout   = (float*)alloc((size_t)N * NF * 4);
  float* a_s    = (float*)alloc((size_t)N * 4 * 4);
  float* a_d    = (float*)alloc((size_t)N * 4 * 4);
  float* gpool  = (float*)alloc(128 * NF * 4);

  k_init<<<cdiv(N, 256), 256, 0, stream>>>(deg, stats, N, 1024);
  k_hist<<<cdiv(E, 256), 256, 0, stream>>>(ei, E, deg);
  k_scan<<<1, 1024, 0, stream>>>(deg, off, cursor, N);
  k_scatter<<<cdiv(total, 256), 256, 0, stream>>>(ei, E, N, cursor, esrc, edst);

  k_colstats<<<256, 256, 0, stream>>>(x, N, stats);
  k_bnx<<<1024, 256, 0, stream>>>(x, stats, hbuf, N);

  for (int L = 0; L < 4; ++L){
    k_gemm<<<cdiv(N, 32), 256, 0, stream>>>(hbuf, gat_lin + (size_t)L * NF * NF, tmp, N);
    k_attvec<<<cdiv(N, 4), 256, 0, stream>>>(tmp, att_src + (size_t)L * NF, att_dst + (size_t)L * NF,
                                             a_s, a_d, N);
    k_edgealpha<<<cdiv(total, 256), 256, 0, stream>>>(esrc, edst, (const float4*)a_s,
                                                      (const float4*)a_d, ealpha, total);
    k_attn<<<cdiv(N, 4), 256, 0, stream>>>(tmp, ealpha, off, esrc,
                                           gat_bias + (size_t)L * NF, gout, N, total);
    if (L == 0){
      k_relu<<<1024, 256, 0, stream>>>(gout, hbuf, (size_t)N * (NF / 4));
    } else {
      k_colstats<<<256, 256, 0, stream>>>(gout, N, stats + L * 256);
      k_bnres<<<1024, 256, 0, stream>>>(gout, stats + L * 256, hbuf, N);
    }
  }

  k_pool<<<128, 256, 0, stream>>>(hbuf, batch, gpool, N);
  k_head<<<1, 1024, 0, stream>>>(gpool, fc_w, fc_b, cls_w, cls_b, out);
}

// Round 3
// 713.753 us; speedup vs baseline: 1.5855x; 1.1492x over previous
//
#include <hip/hip_runtime.h>
#include <math.h>

#define NF 128
#define EPS 1e-5f
#define BNB 1e-4f

static inline int cdiv(int a, int b){ return (a + b - 1) / b; }

__device__ __forceinline__ float lrelu(float x){ return x > 0.f ? x : 0.2f * x; }

// ---------------- CSR build ----------------
__global__ void k_init(int* deg, float* stats, int n, int statcount){
  int i = blockIdx.x * blockDim.x + threadIdx.x;
  if (i < n) deg[i] = 1;                // self-loop contributes 1
  if (i < statcount) stats[i] = 0.f;
}

__global__ void k_hist(const int* __restrict__ ei, int E, int* __restrict__ deg){
  int e = blockIdx.x * blockDim.x + threadIdx.x;
  if (e < E) atomicAdd(&deg[ei[E + e]], 1);
}

// ---- 3-phase multi-block exclusive scan (thread i <-> element i) ----
__global__ __launch_bounds__(256) void k_scan1(const int* __restrict__ deg, int* __restrict__ bsum, int n){
  int i = blockIdx.x * 256 + threadIdx.x;
  int v = (i < n) ? deg[i] : 0;
  int lane = threadIdx.x & 63, w = threadIdx.x >> 6;
  int s = v;
  #pragma unroll
  for (int d = 1; d < 64; d <<= 1) s += __shfl_xor(s, d, 64);
  __shared__ int ws_[4];
  if (lane == 0) ws_[w] = s;
  __syncthreads();
  if (threadIdx.x == 0) bsum[blockIdx.x] = ws_[0] + ws_[1] + ws_[2] + ws_[3];
}

__global__ __launch_bounds__(256) void k_scan2(int* __restrict__ bsum, int nb){
  int t = threadIdx.x;
  int v = (t < nb) ? bsum[t] : 0;
  int lane = t & 63, w = t >> 6;
  int x = v;
  #pragma unroll
  for (int d = 1; d < 64; d <<= 1){
    int y = __shfl_up(x, d, 64);
    if (lane >= d) x += y;
  }
  __shared__ int wt[4], wex[4];
  if (lane == 63) wt[w] = x;
  __syncthreads();
  if (t == 0){ int r = 0; for (int i = 0; i < 4; ++i){ wex[i] = r; r += wt[i]; } }
  __syncthreads();
  if (t < nb) bsum[t] = wex[w] + x - v;   // exclusive
}

__global__ __launch_bounds__(256) void k_scan3(const int* __restrict__ deg, const int* __restrict__ bsum,
                                               int* __restrict__ off, int* __restrict__ cursor, int n){
  int i = blockIdx.x * 256 + threadIdx.x;
  int v = (i < n) ? deg[i] : 0;
  int lane = threadIdx.x & 63, w = threadIdx.x >> 6;
  int x = v;
  #pragma unroll
  for (int d = 1; d < 64; d <<= 1){
    int y = __shfl_up(x, d, 64);
    if (lane >= d) x += y;
  }
  __shared__ int wt[4], wex[4];
  if (lane == 63) wt[w] = x;
  __syncthreads();
  if (threadIdx.x == 0){ int r = 0; for (int j = 0; j < 4; ++j){ wex[j] = r; r += wt[j]; } }
  __syncthreads();
  int excl = bsum[blockIdx.x] + wex[w] + (x - v);
  if (i < n){ off[i] = excl; cursor[i] = excl; }
  if (i == n - 1) off[n] = excl + v;
}

__global__ void k_scatter(const int* __restrict__ ei, int E, int n,
                          int* __restrict__ cursor, int* __restrict__ esrc,
                          int* __restrict__ edst){
  int i = blockIdx.x * blockDim.x + threadIdx.x;
  int total = E + n;
  if (i >= total) return;
  int s, d;
  if (i < E){ s = ei[i]; d = ei[E + i]; }
  else { s = i - E; d = s; }
  int pos = atomicAdd(&cursor[d], 1);
  esrc[pos] = s;
  edst[pos] = d;
}

// ---------------- BN column stats (sum, sumsq into stats[0..127], stats[128..255]) ----------------
__global__ __launch_bounds__(256) void k_colstats(const float* __restrict__ X, int n, float* __restrict__ out){
  __shared__ float ss[4][128], sq[4][128];
  int t = threadIdx.x, lane = t & 63, w = t >> 6;
  float sx = 0.f, sy = 0.f, qx = 0.f, qy = 0.f;
  for (int r = blockIdx.x * 4 + w; r < n; r += gridDim.x * 4){
    float2 v = *(const float2*)(X + (size_t)r * NF + lane * 2);
    sx += v.x; sy += v.y; qx += v.x * v.x; qy += v.y * v.y;
  }
  ss[w][lane * 2] = sx; ss[w][lane * 2 + 1] = sy;
  sq[w][lane * 2] = qx; sq[w][lane * 2 + 1] = qy;
  __syncthreads();
  if (t < 128){
    float tot = ss[0][t] + ss[1][t] + ss[2][t] + ss[3][t];
    atomicAdd(&out[t], tot);
  } else {
    int c = t - 128;
    float tot = sq[0][c] + sq[1][c] + sq[2][c] + sq[3][c];
    atomicAdd(&out[128 + c], tot);
  }
}

// H = (X - m) * rsqrt(var+eps) + BNB
__global__ void k_bnx(const float* __restrict__ X, const float* __restrict__ stats,
                      float* __restrict__ H, int n){
  size_t tot4 = (size_t)n * (NF / 4);
  float inv_n = 1.f / (float)n;
  for (size_t i = blockIdx.x * (size_t)blockDim.x + threadIdx.x; i < tot4;
       i += (size_t)gridDim.x * blockDim.x){
    float4 v = ((const float4*)X)[i];
    int c0 = (int)((i * 4) % NF);
    float* vv = (float*)&v;
    #pragma unroll
    for (int j = 0; j < 4; ++j){
      float m = stats[c0 + j] * inv_n;
      float var = stats[128 + c0 + j] * inv_n - m * m;
      vv[j] = (vv[j] - m) * rsqrtf(var + EPS) + BNB;
    }
    ((float4*)H)[i] = v;
  }
}

// H = relu( (Xg - m)*inv + BNB + H )
__global__ void k_bnres(const float* __restrict__ Xg, const float* __restrict__ stats,
                        float* __restrict__ H, int n){
  size_t tot4 = (size_t)n * (NF / 4);
  float inv_n = 1.f / (float)n;
  for (size_t i = blockIdx.x * (size_t)blockDim.x + threadIdx.x; i < tot4;
       i += (size_t)gridDim.x * blockDim.x){
    float4 v = ((const float4*)Xg)[i];
    float4 hc = ((const float4*)H)[i];
    int c0 = (int)((i * 4) % NF);
    float* vv = (float*)&v;
    float* hh = (float*)&hc;
    #pragma unroll
    for (int j = 0; j < 4; ++j){
      float m = stats[c0 + j] * inv_n;
      float var = stats[128 + c0 + j] * inv_n - m * m;
      float z = (vv[j] - m) * rsqrtf(var + EPS) + BNB + hh[j];
      hh[j] = fmaxf(z, 0.f);
    }
    ((float4*)H)[i] = hc;
  }
}

__global__ void k_relu(const float* __restrict__ X, float* __restrict__ H, size_t tot4){
  for (size_t i = blockIdx.x * (size_t)blockDim.x + threadIdx.x; i < tot4;
       i += (size_t)gridDim.x * blockDim.x){
    float4 v = ((const float4*)X)[i];
    v.x = fmaxf(v.x, 0.f); v.y = fmaxf(v.y, 0.f);
    v.z = fmaxf(v.z, 0.f); v.w = fmaxf(v.w, 0.f);
    ((float4*)H)[i] = v;
  }
}

// ---------------- GEMM: Y[n,128] = X[n,128] @ W[128,128] ----------------
__global__ __launch_bounds__(256) void k_gemm(const float* __restrict__ X, const float* __restrict__ W,
                                              float* __restrict__ Y, int n){
  __shared__ float sW[128 * 128];
  __shared__ float sX[32 * 128];
  int t = threadIdx.x;
  #pragma unroll
  for (int i = 0; i < 16; ++i){
    int i4 = t + 256 * i;
    ((float4*)sW)[i4] = ((const float4*)W)[i4];
  }
  int rbase = blockIdx.x * 32;
  #pragma unroll
  for (int i = 0; i < 4; ++i){
    int i4 = t + 256 * i;
    int row = i4 >> 5, c4 = i4 & 31;
    int gr = rbase + row;
    float4 v = (gr < n) ? ((const float4*)(X + (size_t)gr * NF))[c4] : make_float4(0, 0, 0, 0);
    ((float4*)sX)[i4] = v;
  }
  __syncthreads();
  int c0 = (t & 31) * 4;
  int r0 = (t >> 5) * 4;
  float4 acc[4];
  #pragma unroll
  for (int i = 0; i < 4; ++i) acc[i] = make_float4(0, 0, 0, 0);
  for (int k4 = 0; k4 < 32; ++k4){
    float4 xv[4], wv[4];
    #pragma unroll
    for (int i = 0; i < 4; ++i) xv[i] = *(const float4*)&sX[(r0 + i) * 128 + k4 * 4];
    #pragma unroll
    for (int j = 0; j < 4; ++j) wv[j] = *(const float4*)&sW[(k4 * 4 + j) * 128 + c0];
    #pragma unroll
    for (int i = 0; i < 4; ++i){
      const float* xp = (const float*)&xv[i];
      float* ap = (float*)&acc[i];
      #pragma unroll
      for (int j = 0; j < 4; ++j){
        const float* wp = (const float*)&wv[j];
        float xs = xp[j];
        ap[0] += xs * wp[0]; ap[1] += xs * wp[1];
        ap[2] += xs * wp[2]; ap[3] += xs * wp[3];
      }
    }
  }
  #pragma unroll
  for (int i = 0; i < 4; ++i){
    int gr = rbase + r0 + i;
    if (gr < n) *(float4*)(Y + (size_t)gr * NF + c0) = acc[i];
  }
}

// ---------------- per-node attention coefficients a_s, a_d ----------------
__global__ __launch_bounds__(256) void k_attvec(const float* __restrict__ Hm, const float* __restrict__ asrc,
                                                const float* __restrict__ adst, float* __restrict__ a_s,
                                                float* __restrict__ a_d, int n){
  int t = threadIdx.x, lane = t & 63, w = t >> 6;
  int r = blockIdx.x * 4 + w;
  if (r >= n) return;
  float2 v = *(const float2*)(Hm + (size_t)r * NF + lane * 2);
  float2 us = *(const float2*)(asrc + lane * 2);
  float2 ud = *(const float2*)(adst + lane * 2);
  float ps = v.x * us.x + v.y * us.y;
  float pd = v.x * ud.x + v.y * ud.y;
  #pragma unroll
  for (int d = 1; d < 16; d <<= 1){
    ps += __shfl_xor(ps, d, 64);
    pd += __shfl_xor(pd, d, 64);
  }
  if ((lane & 15) == 0){
    int h = lane >> 4;
    a_s[(size_t)r * 4 + h] = ps;
    a_d[(size_t)r * 4 + h] = pd;
  }
}

// ---------------- per-edge alpha, SoA by head: ealpha[h*total + e] ----------------
__global__ void k_edgealpha(const int* __restrict__ esrc, const int* __restrict__ edst,
                            const float4* __restrict__ a_s, const float4* __restrict__ a_d,
                            float* __restrict__ ealpha, int total){
  int e = blockIdx.x * blockDim.x + threadIdx.x;
  if (e >= total) return;
  float4 as = a_s[esrc[e]];
  float4 ad = a_d[edst[e]];
  ealpha[e]             = lrelu(as.x + ad.x);
  ealpha[total + e]     = lrelu(as.y + ad.y);
  ealpha[2 * total + e] = lrelu(as.z + ad.z);
  ealpha[3 * total + e] = lrelu(as.w + ad.w);
}

// ---------------- attention: single-pass online softmax + aggregate, unroll 4 ----------------
__global__ __launch_bounds__(256) void k_attn(const float* __restrict__ Hm,
                                              const float* __restrict__ ealpha,
                                              const int* __restrict__ off,
                                              const int* __restrict__ esrc,
                                              const float* __restrict__ bias,
                                              float* __restrict__ Y, int n, int estride){
  int t = threadIdx.x, lane = t & 63, w = t >> 6;
  int node = blockIdx.x * 4 + w;
  if (node >= n) return;
  node = __builtin_amdgcn_readfirstlane(node);
  int head = lane >> 4;
  const float* ep = ealpha + (size_t)head * estride;
  int lo = off[node], hi = off[node + 1];
  lo = __builtin_amdgcn_readfirstlane(lo);
  hi = __builtin_amdgcn_readfirstlane(hi);
  int fo = lane * 2;
  float m = -3.4e38f, sum = 0.f, ax = 0.f, ay = 0.f;
  for (int e = lo; e < hi; e += 4){
    int e1 = min(e + 1, hi - 1), e2 = min(e + 2, hi - 1), e3 = min(e + 3, hi - 1);
    int s0 = esrc[e], s1 = esrc[e1], s2 = esrc[e2], s3 = esrc[e3];
    float a0 = ep[e], a1 = ep[e1], a2 = ep[e2], a3 = ep[e3];
    float2 h0 = *(const float2*)(Hm + (size_t)s0 * NF + fo);
    float2 h1 = *(const float2*)(Hm + (size_t)s1 * NF + fo);
    float2 h2 = *(const float2*)(Hm + (size_t)s2 * NF + fo);
    float2 h3 = *(const float2*)(Hm + (size_t)s3 * NF + fo);
    if (e + 1 >= hi) a1 = -3.4e38f;   // clamped duplicates get weight 0
    if (e + 2 >= hi) a2 = -3.4e38f;
    if (e + 3 >= hi) a3 = -3.4e38f;
    float mm = fmaxf(fmaxf(a0, a1), fmaxf(a2, a3));
    float newm = fmaxf(m, mm);
    float c = __expf(m - newm);
    float w0 = __expf(a0 - newm), w1 = __expf(a1 - newm);
    float w2 = __expf(a2 - newm), w3 = __expf(a3 - newm);
    sum = sum * c + (w0 + w1 + w2 + w3);
    ax = ax * c + w0 * h0.x + w1 * h1.x + w2 * h2.x + w3 * h3.x;
    ay = ay * c + w0 * h0.y + w1 * h1.y + w2 * h2.y + w3 * h3.y;
    m = newm;
  }
  float inv = 1.f / (sum + 1e-16f);
  float2 b = *(const float2*)(bias + fo);
  float2 r;
  r.x = ax * inv + b.x;
  r.y = ay * inv + b.y;
  *(float2*)(Y + (size_t)node * NF + fo) = r;
}

// ---------------- pooling: batch is sorted; one block per graph ----------------
__global__ __launch_bounds__(256) void k_pool(const float* __restrict__ H, const int* __restrict__ batch,
                                              float* __restrict__ g, int n){
  int gid = blockIdx.x;
  int t = threadIdx.x, lane = t & 63, w = t >> 6;
  int lo = 0, hi = n;
  while (lo < hi){ int mid = (lo + hi) >> 1; if (batch[mid] < gid) lo = mid + 1; else hi = mid; }
  int a = lo, b = n;
  while (a < b){ int mid = (a + b) >> 1; if (batch[mid] < gid + 1) a = mid + 1; else b = mid; }
  float sx = 0.f, sy = 0.f;
  for (int r = lo + w; r < a; r += 4){
    float2 v = *(const float2*)(H + (size_t)r * NF + lane * 2);
    sx += v.x; sy += v.y;
  }
  __shared__ float ss[4][128];
  ss[w][lane * 2] = sx; ss[w][lane * 2 + 1] = sy;
  __syncthreads();
  if (t < 128) g[(size_t)gid * NF + t] = ss[0][t] + ss[1][t] + ss[2][t] + ss[3][t];
}

// ---------------- head: BN -> fc+relu -> BN -> cls -> log_softmax (single block) ----------------
__global__ __launch_bounds__(1024) void k_head(const float* __restrict__ g, const float* __restrict__ fc_w,
                                               const float* __restrict__ fc_b, const float* __restrict__ cls_w,
                                               const float* __restrict__ cls_b, float* __restrict__ out){
  __shared__ float A[128 * 128];
  __shared__ float mbuf[128], ibuf[128];
  __shared__ float logits[256];
  int t = threadIdx.x;
  #pragma unroll
  for (int i = 0; i < 4; ++i)
    ((float4*)A)[t + 1024 * i] = ((const float4*)g)[t + 1024 * i];
  __syncthreads();
  if (t < 128){
    float s = 0.f, q = 0.f;
    for (int r = 0; r < 128; ++r){ float v = A[r * 128 + t]; s += v; q += v * v; }
    float m = s * (1.f / 128.f);
    float var = q * (1.f / 128.f) - m * m;
    mbuf[t] = m; ibuf[t] = rsqrtf(var + EPS);
  }
  __syncthreads();
  #pragma unroll
  for (int i = 0; i < 16; ++i){
    int idx = t + 1024 * i;
    int c = idx & 127;
    A[idx] = (A[idx] - mbuf[c]) * ibuf[c] + BNB;
  }
  __syncthreads();
  int c0 = (t & 31) * 4, r0 = (t >> 5) * 4;
  float o[4][4];
  float4 bb = *(const float4*)(fc_b + c0);
  #pragma unroll
  for (int i = 0; i < 4; ++i){ o[i][0] = bb.x; o[i][1] = bb.y; o[i][2] = bb.z; o[i][3] = bb.w; }
  for (int k = 0; k < 128; ++k){
    float4 wv = *(const float4*)(fc_w + (size_t)k * 128 + c0);
    #pragma unroll
    for (int i = 0; i < 4; ++i){
      float xs = A[(r0 + i) * 128 + k];
      o[i][0] += xs * wv.x; o[i][1] += xs * wv.y;
      o[i][2] += xs * wv.z; o[i][3] += xs * wv.w;
    }
  }
  __syncthreads();
  #pragma unroll
  for (int i = 0; i < 4; ++i)
    #pragma unroll
    for (int j = 0; j < 4; ++j)
      A[(r0 + i) * 128 + c0 + j] = fmaxf(o[i][j], 0.f);
  __syncthreads();
  if (t < 128){
    float s = 0.f, q = 0.f;
    for (int r = 0; r < 128; ++r){ float v = A[r * 128 + t]; s += v; q += v * v; }
    float m = s * (1.f / 128.f);
    float var = q * (1.f / 128.f) - m * m;
    mbuf[t] = m; ibuf[t] = rsqrtf(var + EPS);
  }
  __syncthreads();
  #pragma unroll
  for (int i = 0; i < 16; ++i){
    int idx = t + 1024 * i;
    int c = idx & 127;
    A[idx] = (A[idx] - mbuf[c]) * ibuf[c] + BNB;
  }
  __syncthreads();
  if (t < 256){
    int r = t >> 1, j = t & 1;
    float accv = cls_b[j];
    for (int k = 0; k < 128; ++k) accv += A[r * 128 + k] * cls_w[k * 2 + j];
    logits[t] = accv;
  }
  __syncthreads();
  if (t < 256){
    int r = t >> 1;
    float l0 = logits[r * 2], l1 = logits[r * 2 + 1];
    float mx = fmaxf(l0, l1);
    float lse = mx + logf(__expf(l0 - mx) + __expf(l1 - mx));
    out[t] = logits[t] - lse;
  }
}

extern "C" void kernel_launch(void* const* d_in, const int* in_sizes, int n_in,
                              void* d_out, int out_size, void* d_ws, size_t ws_size,
                              hipStream_t stream){
  const float* x        = (const float*)d_in[0];
  const int*   ei       = (const int*)d_in[1];
  const int*   batch    = (const int*)d_in[2];
  const float* gat_lin  = (const float*)d_in[3];
  const float* att_src  = (const float*)d_in[4];
  const float* att_dst  = (const float*)d_in[5];
  const float* gat_bias = (const float*)d_in[6];
  const float* fc_w     = (const float*)d_in[7];
  const float* fc_b     = (const float*)d_in[8];
  const float* cls_w    = (const float*)d_in[9];
  const float* cls_b    = (const float*)d_in[10];
  float* out = (float*)d_out;
  (void)n_in; (void)out_size; (void)ws_size;

  int N = in_sizes[0] / NF;
  int E = in_sizes[1] / 2;
  int total = E + N;
  int nb = cdiv(N, 256);   // scan blocks (196 for N=50000; k_scan2 handles up to 256)

  char* p = (char*)d_ws;
  auto alloc = [&](size_t bytes) -> char* {
    char* r = p;
    p += (bytes + 255) & ~(size_t)255;
    return r;
  };
  int*   deg    = (int*)alloc((size_t)N * 4);
  int*   off    = (int*)alloc((size_t)(N + 1) * 4);
  int*   cursor = (int*)alloc((size_t)N * 4);
  int*   bsum   = (int*)alloc((size_t)nb * 4);
  int*   esrc   = (int*)alloc((size_t)total * 4);
  int*   edst   = (int*)alloc((size_t)total * 4);
  float* ealpha = (float*)alloc((size_t)total * 4 * 4);
  float* stats  = (float*)alloc(4 * 256 * 4);
  float* hbuf   = (float*)alloc((size_t)N * NF * 4);
  float* tmp    = (float*)alloc((size_t)N * NF * 4);
  float* gout   = (float*)alloc((size_t)N * NF * 4);
  float* a_s    = (float*)alloc((size_t)N * 4 * 4);
  float* a_d    = (float*)alloc((size_t)N * 4 * 4);
  float* gpool  = (float*)alloc(128 * NF * 4);

  k_init<<<cdiv(N, 256), 256, 0, stream>>>(deg, stats, N, 1024);
  k_hist<<<cdiv(E, 256), 256, 0, stream>>>(ei, E, deg);
  k_scan1<<<nb, 256, 0, stream>>>(deg, bsum, N);
  k_scan2<<<1, 256, 0, stream>>>(bsum, nb);
  k_scan3<<<nb, 256, 0, stream>>>(deg, bsum, off, cursor, N);
  k_scatter<<<cdiv(total, 256), 256, 0, stream>>>(ei, E, N, cursor, esrc, edst);

  k_colstats<<<256, 256, 0, stream>>>(x, N, stats);
  k_bnx<<<1024, 256, 0, stream>>>(x, stats, hbuf, N);

  for (int L = 0; L < 4; ++L){
    k_gemm<<<cdiv(N, 32), 256, 0, stream>>>(hbuf, gat_lin + (size_t)L * NF * NF, tmp, N);
    k_attvec<<<cdiv(N, 4), 256, 0, stream>>>(tmp, att_src + (size_t)L * NF, att_dst + (size_t)L * NF,
                                             a_s, a_d, N);
    k_edgealpha<<<cdiv(total, 256), 256, 0, stream>>>(esrc, edst, (const float4*)a_s,
                                                      (const float4*)a_d, ealpha, total);
    k_attn<<<cdiv(N, 4), 256, 0, stream>>>(tmp, ealpha, off, esrc,
                                           gat_bias + (size_t)L * NF, gout, N, total);
    if (L == 0){
      k_relu<<<1024, 256, 0, stream>>>(gout, hbuf, (size_t)N * (NF / 4));
    } else {
      k_colstats<<<256, 256, 0, stream>>>(gout, N, stats + L * 256);
      k_bnres<<<1024, 256, 0, stream>>>(gout, stats + L * 256, hbuf, N);
    }
  }

  k_pool<<<128, 256, 0, stream>>>(hbuf, batch, gpool, N);
  k_head<<<1, 1024, 0, stream>>>(gpool, fc_w, fc_b, cls_w, cls_b, out);
}

// Round 4
// 539.083 us; speedup vs baseline: 2.0993x; 1.3240x over previous
//
#include <hip/hip_runtime.h>
#include <math.h>

#define NF 128
#define EPS 1e-5f
#define BNB 1e-4f

static inline int cdiv(int a, int b){ return (a + b - 1) / b; }

typedef __attribute__((ext_vector_type(8))) short bf16x8;
typedef __attribute__((ext_vector_type(4))) float f32x4;

__device__ __forceinline__ float lrelu(float x){ return x > 0.f ? x : 0.2f * x; }

// f32 -> bf16 round-to-nearest-even (finite inputs)
__device__ __forceinline__ unsigned short f2b(float f){
  unsigned u = __float_as_uint(f);
  u += 0x7fffu + ((u >> 16) & 1u);
  return (unsigned short)(u >> 16);
}
__device__ __forceinline__ float b2f_lo(unsigned v){ return __uint_as_float(v << 16); }
__device__ __forceinline__ float b2f_hi(unsigned v){ return __uint_as_float(v & 0xffff0000u); }

// ---------------- CSR build ----------------
__global__ void k_init(int* deg, float* stats, int n, int statcount){
  int i = blockIdx.x * blockDim.x + threadIdx.x;
  if (i < n) deg[i] = 1;                // self-loop contributes 1
  if (i < statcount) stats[i] = 0.f;
}

__global__ void k_hist(const int* __restrict__ ei, int E, int* __restrict__ deg){
  int e = blockIdx.x * blockDim.x + threadIdx.x;
  if (e < E) atomicAdd(&deg[ei[E + e]], 1);
}

// ---- 3-phase multi-block exclusive scan (thread i <-> element i) ----
__global__ __launch_bounds__(256) void k_scan1(const int* __restrict__ deg, int* __restrict__ bsum, int n){
  int i = blockIdx.x * 256 + threadIdx.x;
  int v = (i < n) ? deg[i] : 0;
  int lane = threadIdx.x & 63, w = threadIdx.x >> 6;
  int s = v;
  #pragma unroll
  for (int d = 1; d < 64; d <<= 1) s += __shfl_xor(s, d, 64);
  __shared__ int ws_[4];
  if (lane == 0) ws_[w] = s;
  __syncthreads();
  if (threadIdx.x == 0) bsum[blockIdx.x] = ws_[0] + ws_[1] + ws_[2] + ws_[3];
}

__global__ __launch_bounds__(256) void k_scan2(int* __restrict__ bsum, int nb){
  int t = threadIdx.x;
  int v = (t < nb) ? bsum[t] : 0;
  int lane = t & 63, w = t >> 6;
  int x = v;
  #pragma unroll
  for (int d = 1; d < 64; d <<= 1){
    int y = __shfl_up(x, d, 64);
    if (lane >= d) x += y;
  }
  __shared__ int wt[4], wex[4];
  if (lane == 63) wt[w] = x;
  __syncthreads();
  if (t == 0){ int r = 0; for (int i = 0; i < 4; ++i){ wex[i] = r; r += wt[i]; } }
  __syncthreads();
  if (t < nb) bsum[t] = wex[w] + x - v;   // exclusive
}

__global__ __launch_bounds__(256) void k_scan3(const int* __restrict__ deg, const int* __restrict__ bsum,
                                               int* __restrict__ off, int* __restrict__ cursor, int n){
  int i = blockIdx.x * 256 + threadIdx.x;
  int v = (i < n) ? deg[i] : 0;
  int lane = threadIdx.x & 63, w = threadIdx.x >> 6;
  int x = v;
  #pragma unroll
  for (int d = 1; d < 64; d <<= 1){
    int y = __shfl_up(x, d, 64);
    if (lane >= d) x += y;
  }
  __shared__ int wt[4], wex[4];
  if (lane == 63) wt[w] = x;
  __syncthreads();
  if (threadIdx.x == 0){ int r = 0; for (int j = 0; j < 4; ++j){ wex[j] = r; r += wt[j]; } }
  __syncthreads();
  int excl = bsum[blockIdx.x] + wex[w] + (x - v);
  if (i < n){ off[i] = excl; cursor[i] = excl; }
  if (i == n - 1) off[n] = excl + v;
}

__global__ void k_scatter(const int* __restrict__ ei, int E, int n,
                          int* __restrict__ cursor, int* __restrict__ esrc,
                          int* __restrict__ edst){
  int i = blockIdx.x * blockDim.x + threadIdx.x;
  int total = E + n;
  if (i >= total) return;
  int s, d;
  if (i < E){ s = ei[i]; d = ei[E + i]; }
  else { s = i - E; d = s; }
  int pos = atomicAdd(&cursor[d], 1);
  esrc[pos] = s;
  edst[pos] = d;
}

// ---------------- weight convert + transpose: Wt[l][n][k] bf16 ----------------
__global__ void k_cvtw(const float* __restrict__ W, unsigned short* __restrict__ Wt){
  int i = blockIdx.x * blockDim.x + threadIdx.x;   // 4*128*128
  int l = i >> 14, rem = i & 16383;
  int k = rem >> 7, nn = rem & 127;
  Wt[(l << 14) + nn * 128 + k] = f2b(W[i]);
}

// ---------------- BN column stats (sum, sumsq into stats[0..127], stats[128..255]) ----------------
__global__ __launch_bounds__(256) void k_colstats(const float* __restrict__ X, int n, float* __restrict__ out){
  __shared__ float ss[4][128], sq[4][128];
  int t = threadIdx.x, lane = t & 63, w = t >> 6;
  float sx = 0.f, sy = 0.f, qx = 0.f, qy = 0.f;
  for (int r = blockIdx.x * 4 + w; r < n; r += gridDim.x * 4){
    float2 v = *(const float2*)(X + (size_t)r * NF + lane * 2);
    sx += v.x; sy += v.y; qx += v.x * v.x; qy += v.y * v.y;
  }
  ss[w][lane * 2] = sx; ss[w][lane * 2 + 1] = sy;
  sq[w][lane * 2] = qx; sq[w][lane * 2 + 1] = qy;
  __syncthreads();
  if (t < 128){
    float tot = ss[0][t] + ss[1][t] + ss[2][t] + ss[3][t];
    atomicAdd(&out[t], tot);
  } else {
    int c = t - 128;
    float tot = sq[0][c] + sq[1][c] + sq[2][c] + sq[3][c];
    atomicAdd(&out[128 + c], tot);
  }
}

// H = (X - m) * rsqrt(var+eps) + BNB   (writes f32 + bf16 copy)
__global__ void k_bnx(const float* __restrict__ X, const float* __restrict__ stats,
                      float* __restrict__ H, ushort4* __restrict__ H16, int n){
  size_t tot4 = (size_t)n * (NF / 4);
  float inv_n = 1.f / (float)n;
  for (size_t i = blockIdx.x * (size_t)blockDim.x + threadIdx.x; i < tot4;
       i += (size_t)gridDim.x * blockDim.x){
    float4 v = ((const float4*)X)[i];
    int c0 = (int)((i * 4) % NF);
    float* vv = (float*)&v;
    #pragma unroll
    for (int j = 0; j < 4; ++j){
      float m = stats[c0 + j] * inv_n;
      float var = stats[128 + c0 + j] * inv_n - m * m;
      vv[j] = (vv[j] - m) * rsqrtf(var + EPS) + BNB;
    }
    ((float4*)H)[i] = v;
    ushort4 b;
    b.x = f2b(v.x); b.y = f2b(v.y); b.z = f2b(v.z); b.w = f2b(v.w);
    H16[i] = b;
  }
}

// H = relu( (Xg - m)*inv + BNB + H )   (writes f32 + bf16 copy)
__global__ void k_bnres(const float* __restrict__ Xg, const float* __restrict__ stats,
                        float* __restrict__ H, ushort4* __restrict__ H16, int n){
  size_t tot4 = (size_t)n * (NF / 4);
  float inv_n = 1.f / (float)n;
  for (size_t i = blockIdx.x * (size_t)blockDim.x + threadIdx.x; i < tot4;
       i += (size_t)gridDim.x * blockDim.x){
    float4 v = ((const float4*)Xg)[i];
    float4 hc = ((const float4*)H)[i];
    int c0 = (int)((i * 4) % NF);
    float* vv = (float*)&v;
    float* hh = (float*)&hc;
    #pragma unroll
    for (int j = 0; j < 4; ++j){
      float m = stats[c0 + j] * inv_n;
      float var = stats[128 + c0 + j] * inv_n - m * m;
      float z = (vv[j] - m) * rsqrtf(var + EPS) + BNB + hh[j];
      hh[j] = fmaxf(z, 0.f);
    }
    ((float4*)H)[i] = hc;
    ushort4 b;
    b.x = f2b(hc.x); b.y = f2b(hc.y); b.z = f2b(hc.z); b.w = f2b(hc.w);
    H16[i] = b;
  }
}

__global__ void k_relu(const float* __restrict__ X, float* __restrict__ H,
                       ushort4* __restrict__ H16, size_t tot4){
  for (size_t i = blockIdx.x * (size_t)blockDim.x + threadIdx.x; i < tot4;
       i += (size_t)gridDim.x * blockDim.x){
    float4 v = ((const float4*)X)[i];
    v.x = fmaxf(v.x, 0.f); v.y = fmaxf(v.y, 0.f);
    v.z = fmaxf(v.z, 0.f); v.w = fmaxf(v.w, 0.f);
    ((float4*)H)[i] = v;
    ushort4 b;
    b.x = f2b(v.x); b.y = f2b(v.y); b.z = f2b(v.z); b.w = f2b(v.w);
    H16[i] = b;
  }
}

// ---------------- MFMA GEMM: Y16[n,128] = X16[n,128] @ W (Wt is [n][k] bf16) ----------------
// block = 64 rows; 4 waves, wave w -> rows w*16..w*16+15, all 128 cols.
// A frag: lane l row=l&15, k=8*(l>>4)+i ; B frag: col=l&15, same k ; D: row=4*(l>>4)+i, col=l&15.
__global__ __launch_bounds__(256) void k_gemm(const unsigned short* __restrict__ X,
                                              const unsigned short* __restrict__ Wt,
                                              unsigned short* __restrict__ Y, int n){
  __shared__ unsigned short sX[64 * 128];    // 16 KB, XOR-swizzled 16B units
  __shared__ unsigned short sW[128 * 128];   // 32 KB, [n][k], XOR-swizzled
  int t = threadIdx.x;
  int rbase = blockIdx.x * 64;
  #pragma unroll
  for (int i = 0; i < 8; ++i){               // stage Wt: 2048 uint4
    int idx = t + 256 * i;
    int rn = idx >> 4, c16 = idx & 15;
    uint4 v = ((const uint4*)Wt)[idx];
    *(uint4*)&sW[rn * 128 + ((c16 ^ (rn & 7)) << 3)] = v;
  }
  #pragma unroll
  for (int i = 0; i < 4; ++i){               // stage X: 1024 uint4
    int idx = t + 256 * i;
    int r = idx >> 4, c16 = idx & 15;
    int gr = rbase + r;
    uint4 v = (gr < n) ? ((const uint4*)(X + (size_t)gr * NF))[c16] : make_uint4(0, 0, 0, 0);
    *(uint4*)&sX[r * 128 + ((c16 ^ (r & 7)) << 3)] = v;
  }
  __syncthreads();
  int lane = t & 63, w = t >> 6;
  int lrow = w * 16 + (lane & 15);
  int khi = lane >> 4;                       // 0..3
  bf16x8 a[4];
  #pragma unroll
  for (int ks = 0; ks < 4; ++ks){
    int c16 = ks * 4 + khi;
    a[ks] = *(const bf16x8*)&sX[lrow * 128 + ((c16 ^ (lrow & 7)) << 3)];
  }
  f32x4 acc[8];
  #pragma unroll
  for (int nt = 0; nt < 8; ++nt){
    f32x4 z = {0.f, 0.f, 0.f, 0.f};
    acc[nt] = z;
    int nrow = nt * 16 + (lane & 15);
    #pragma unroll
    for (int ks = 0; ks < 4; ++ks){
      int c16 = ks * 4 + khi;
      bf16x8 b = *(const bf16x8*)&sW[nrow * 128 + ((c16 ^ (nrow & 7)) << 3)];
      acc[nt] = __builtin_amdgcn_mfma_f32_16x16x32_bf16(a[ks], b, acc[nt], 0, 0, 0);
    }
  }
  // stage D into own wave's 16 rows of sX (bf16, same 16B swizzle), then coalesced store
  #pragma unroll
  for (int nt = 0; nt < 8; ++nt){
    #pragma unroll
    for (int i = 0; i < 4; ++i){
      int r = w * 16 + (khi << 2) + i;
      int c = nt * 16 + (lane & 15);
      int csw = c ^ ((r & 7) << 3);          // element-level XOR == 16B-unit XOR
      sX[r * 128 + csw] = f2b(acc[nt][i]);
    }
  }
  __syncthreads();
  #pragma unroll
  for (int i = 0; i < 4; ++i){
    int idx = t + 256 * i;
    int r = idx >> 4, c16 = idx & 15;
    int gr = rbase + r;
    if (gr < n)
      ((uint4*)(Y + (size_t)gr * NF))[c16] = *(const uint4*)&sX[r * 128 + ((c16 ^ (r & 7)) << 3)];
  }
}

// ---------------- per-node attention coefficients a_s, a_d (bf16 input) ----------------
__global__ __launch_bounds__(256) void k_attvec(const unsigned short* __restrict__ Hm16,
                                                const float* __restrict__ asrc,
                                                const float* __restrict__ adst, float* __restrict__ a_s,
                                                float* __restrict__ a_d, int n){
  int t = threadIdx.x, lane = t & 63, w = t >> 6;
  int r = blockIdx.x * 4 + w;
  if (r >= n) return;
  unsigned v = *(const unsigned*)(Hm16 + (size_t)r * NF + lane * 2);
  float vx = b2f_lo(v), vy = b2f_hi(v);
  float2 us = *(const float2*)(asrc + lane * 2);
  float2 ud = *(const float2*)(adst + lane * 2);
  float ps = vx * us.x + vy * us.y;
  float pd = vx * ud.x + vy * ud.y;
  #pragma unroll
  for (int d = 1; d < 16; d <<= 1){
    ps += __shfl_xor(ps, d, 64);
    pd += __shfl_xor(pd, d, 64);
  }
  if ((lane & 15) == 0){
    int h = lane >> 4;
    a_s[(size_t)r * 4 + h] = ps;
    a_d[(size_t)r * 4 + h] = pd;
  }
}

// ---------------- per-edge alpha, SoA by head: ealpha[h*total + e] ----------------
__global__ void k_edgealpha(const int* __restrict__ esrc, const int* __restrict__ edst,
                            const float4* __restrict__ a_s, const float4* __restrict__ a_d,
                            float* __restrict__ ealpha, int total){
  int e = blockIdx.x * blockDim.x + threadIdx.x;
  if (e >= total) return;
  float4 as = a_s[esrc[e]];
  float4 ad = a_d[edst[e]];
  ealpha[e]             = lrelu(as.x + ad.x);
  ealpha[total + e]     = lrelu(as.y + ad.y);
  ealpha[2 * total + e] = lrelu(as.z + ad.z);
  ealpha[3 * total + e] = lrelu(as.w + ad.w);
}

// ---------------- attention: single-pass online softmax + aggregate, bf16 payload ----------------
__global__ __launch_bounds__(256) void k_attn(const unsigned short* __restrict__ Hm16,
                                              const float* __restrict__ ealpha,
                                              const int* __restrict__ off,
                                              const int* __restrict__ esrc,
                                              const float* __restrict__ bias,
                                              float* __restrict__ Y, int n, int estride){
  int t = threadIdx.x, lane = t & 63, w = t >> 6;
  int node = blockIdx.x * 4 + w;
  if (node >= n) return;
  node = __builtin_amdgcn_readfirstlane(node);
  int head = lane >> 4;
  const float* ep = ealpha + (size_t)head * estride;
  int lo = off[node], hi = off[node + 1];
  lo = __builtin_amdgcn_readfirstlane(lo);
  hi = __builtin_amdgcn_readfirstlane(hi);
  int fo = lane * 2;
  float m = -3.4e38f, sum = 0.f, ax = 0.f, ay = 0.f;
  for (int e = lo; e < hi; e += 4){
    int e1 = min(e + 1, hi - 1), e2 = min(e + 2, hi - 1), e3 = min(e + 3, hi - 1);
    int s0 = esrc[e], s1 = esrc[e1], s2 = esrc[e2], s3 = esrc[e3];
    float a0 = ep[e], a1 = ep[e1], a2 = ep[e2], a3 = ep[e3];
    unsigned v0 = *(const unsigned*)(Hm16 + (size_t)s0 * NF + fo);
    unsigned v1 = *(const unsigned*)(Hm16 + (size_t)s1 * NF + fo);
    unsigned v2 = *(const unsigned*)(Hm16 + (size_t)s2 * NF + fo);
    unsigned v3 = *(const unsigned*)(Hm16 + (size_t)s3 * NF + fo);
    if (e + 1 >= hi) a1 = -3.4e38f;   // clamped duplicates get weight 0
    if (e + 2 >= hi) a2 = -3.4e38f;
    if (e + 3 >= hi) a3 = -3.4e38f;
    float mm = fmaxf(fmaxf(a0, a1), fmaxf(a2, a3));
    float newm = fmaxf(m, mm);
    float c = __expf(m - newm);
    float w0 = __expf(a0 - newm), w1 = __expf(a1 - newm);
    float w2 = __expf(a2 - newm), w3 = __expf(a3 - newm);
    sum = sum * c + (w0 + w1 + w2 + w3);
    ax = ax * c + w0 * b2f_lo(v0) + w1 * b2f_lo(v1) + w2 * b2f_lo(v2) + w3 * b2f_lo(v3);
    ay = ay * c + w0 * b2f_hi(v0) + w1 * b2f_hi(v1) + w2 * b2f_hi(v2) + w3 * b2f_hi(v3);
    m = newm;
  }
  float inv = 1.f / (sum + 1e-16f);
  float2 b = *(const float2*)(bias + fo);
  float2 r;
  r.x = ax * inv + b.x;
  r.y = ay * inv + b.y;
  *(float2*)(Y + (size_t)node * NF + fo) = r;
}

// ---------------- pooling: batch is sorted; one block per graph ----------------
__global__ __launch_bounds__(256) void k_pool(const float* __restrict__ H, const int* __restrict__ batch,
                                              float* __restrict__ g, int n){
  int gid = blockIdx.x;
  int t = threadIdx.x, lane = t & 63, w = t >> 6;
  int lo = 0, hi = n;
  while (lo < hi){ int mid = (lo + hi) >> 1; if (batch[mid] < gid) lo = mid + 1; else hi = mid; }
  int a = lo, b = n;
  while (a < b){ int mid = (a + b) >> 1; if (batch[mid] < gid + 1) a = mid + 1; else b = mid; }
  float sx = 0.f, sy = 0.f;
  for (int r = lo + w; r < a; r += 4){
    float2 v = *(const float2*)(H + (size_t)r * NF + lane * 2);
    sx += v.x; sy += v.y;
  }
  __shared__ float ss[4][128];
  ss[w][lane * 2] = sx; ss[w][lane * 2 + 1] = sy;
  __syncthreads();
  if (t < 128) g[(size_t)gid * NF + t] = ss[0][t] + ss[1][t] + ss[2][t] + ss[3][t];
}

// ---------------- head: BN -> fc+relu -> BN -> cls -> log_softmax (single block) ----------------
__global__ __launch_bounds__(1024) void k_head(const float* __restrict__ g, const float* __restrict__ fc_w,
                                               const float* __restrict__ fc_b, const float* __restrict__ cls_w,
                                               const float* __restrict__ cls_b, float* __restrict__ out){
  __shared__ float A[128 * 128];
  __shared__ float mbuf[128], ibuf[128];
  __shared__ float logits[256];
  int t = threadIdx.x;
  #pragma unroll
  for (int i = 0; i < 4; ++i)
    ((float4*)A)[t + 1024 * i] = ((const float4*)g)[t + 1024 * i];
  __syncthreads();
  if (t < 128){
    float s = 0.f, q = 0.f;
    for (int r = 0; r < 128; ++r){ float v = A[r * 128 + t]; s += v; q += v * v; }
    float m = s * (1.f / 128.f);
    float var = q * (1.f / 128.f) - m * m;
    mbuf[t] = m; ibuf[t] = rsqrtf(var + EPS);
  }
  __syncthreads();
  #pragma unroll
  for (int i = 0; i < 16; ++i){
    int idx = t + 1024 * i;
    int c = idx & 127;
    A[idx] = (A[idx] - mbuf[c]) * ibuf[c] + BNB;
  }
  __syncthreads();
  int c0 = (t & 31) * 4, r0 = (t >> 5) * 4;
  float o[4][4];
  float4 bb = *(const float4*)(fc_b + c0);
  #pragma unroll
  for (int i = 0; i < 4; ++i){ o[i][0] = bb.x; o[i][1] = bb.y; o[i][2] = bb.z; o[i][3] = bb.w; }
  for (int k = 0; k < 128; ++k){
    float4 wv = *(const float4*)(fc_w + (size_t)k * 128 + c0);
    #pragma unroll
    for (int i = 0; i < 4; ++i){
      float xs = A[(r0 + i) * 128 + k];
      o[i][0] += xs * wv.x; o[i][1] += xs * wv.y;
      o[i][2] += xs * wv.z; o[i][3] += xs * wv.w;
    }
  }
  __syncthreads();
  #pragma unroll
  for (int i = 0; i < 4; ++i)
    #pragma unroll
    for (int j = 0; j < 4; ++j)
      A[(r0 + i) * 128 + c0 + j] = fmaxf(o[i][j], 0.f);
  __syncthreads();
  if (t < 128){
    float s = 0.f, q = 0.f;
    for (int r = 0; r < 128; ++r){ float v = A[r * 128 + t]; s += v; q += v * v; }
    float m = s * (1.f / 128.f);
    float var = q * (1.f / 128.f) - m * m;
    mbuf[t] = m; ibuf[t] = rsqrtf(var + EPS);
  }
  __syncthreads();
  #pragma unroll
  for (int i = 0; i < 16; ++i){
    int idx = t + 1024 * i;
    int c = idx & 127;
    A[idx] = (A[idx] - mbuf[c]) * ibuf[c] + BNB;
  }
  __syncthreads();
  if (t < 256){
    int r = t >> 1, j = t & 1;
    float accv = cls_b[j];
    for (int k = 0; k < 128; ++k) accv += A[r * 128 + k] * cls_w[k * 2 + j];
    logits[t] = accv;
  }
  __syncthreads();
  if (t < 256){
    int r = t >> 1;
    float l0 = logits[r * 2], l1 = logits[r * 2 + 1];
    float mx = fmaxf(l0, l1);
    float lse = mx + logf(__expf(l0 - mx) + __expf(l1 - mx));
    out[t] = logits[t] - lse;
  }
}

extern "C" void kernel_launch(void* const* d_in, const int* in_sizes, int n_in,
                              void* d_out, int out_size, void* d_ws, size_t ws_size,
                              hipStream_t stream){
  const float* x        = (const float*)d_in[0];
  const int*   ei       = (const int*)d_in[1];
  const int*   batch    = (const int*)d_in[2];
  const float* gat_lin  = (const float*)d_in[3];
  const float* att_src  = (const float*)d_in[4];
  const float* att_dst  = (const float*)d_in[5];
  const float* gat_bias = (const float*)d_in[6];
  const float* fc_w     = (const float*)d_in[7];
  const float* fc_b     = (const float*)d_in[8];
  const float* cls_w    = (const float*)d_in[9];
  const float* cls_b    = (const float*)d_in[10];
  float* out = (float*)d_out;
  (void)n_in; (void)out_size; (void)ws_size;

  int N = in_sizes[0] / NF;
  int E = in_sizes[1] / 2;
  int total = E + N;
  int nb = cdiv(N, 256);   // scan blocks (196 for N=50000; k_scan2 handles up to 256)

  char* p = (char*)d_ws;
  auto alloc = [&](size_t bytes) -> char* {
    char* r = p;
    p += (bytes + 255) & ~(size_t)255;
    return r;
  };
  int*   deg    = (int*)alloc((size_t)N * 4);
  int*   off    = (int*)alloc((size_t)(N + 1) * 4);
  int*   cursor = (int*)alloc((size_t)N * 4);
  int*   bsum   = (int*)alloc((size_t)nb * 4);
  int*   esrc   = (int*)alloc((size_t)total * 4);
  int*   edst   = (int*)alloc((size_t)total * 4);
  float* ealpha = (float*)alloc((size_t)total * 4 * 4);
  float* stats  = (float*)alloc(4 * 256 * 4);
  float* hbuf   = (float*)alloc((size_t)N * NF * 4);
  unsigned short* hbuf16 = (unsigned short*)alloc((size_t)N * NF * 2);
  unsigned short* tmp16  = (unsigned short*)alloc((size_t)N * NF * 2);
  unsigned short* wbuf16 = (unsigned short*)alloc((size_t)4 * NF * NF * 2);
  float* gout   = (float*)alloc((size_t)N * NF * 4);
  float* a_s    = (float*)alloc((size_t)N * 4 * 4);
  float* a_d    = (float*)alloc((size_t)N * 4 * 4);
  float* gpool  = (float*)alloc(128 * NF * 4);

  k_init<<<cdiv(N, 256), 256, 0, stream>>>(deg, stats, N, 1024);
  k_hist<<<cdiv(E, 256), 256, 0, stream>>>(ei, E, deg);
  k_scan1<<<nb, 256, 0, stream>>>(deg, bsum, N);
  k_scan2<<<1, 256, 0, stream>>>(bsum, nb);
  k_scan3<<<nb, 256, 0, stream>>>(deg, bsum, off, cursor, N);
  k_scatter<<<cdiv(total, 256), 256, 0, stream>>>(ei, E, N, cursor, esrc, edst);
  k_cvtw<<<256, 256, 0, stream>>>(gat_lin, wbuf16);

  k_colstats<<<256, 256, 0, stream>>>(x, N, stats);
  k_bnx<<<1024, 256, 0, stream>>>(x, stats, hbuf, (ushort4*)hbuf16, N);

  for (int L = 0; L < 4; ++L){
    k_gemm<<<cdiv(N, 64), 256, 0, stream>>>(hbuf16, wbuf16 + (size_t)L * NF * NF, tmp16, N);
    k_attvec<<<cdiv(N, 4), 256, 0, stream>>>(tmp16, att_src + (size_t)L * NF, att_dst + (size_t)L * NF,
                                             a_s, a_d, N);
    k_edgealpha<<<cdiv(total, 256), 256, 0, stream>>>(esrc, edst, (const float4*)a_s,
                                                      (const float4*)a_d, ealpha, total);
    k_attn<<<cdiv(N, 4), 256, 0, stream>>>(tmp16, ealpha, off, esrc,
                                           gat_bias + (size_t)L * NF, gout, N, total);
    if (L == 0){
      k_relu<<<1024, 256, 0, stream>>>(gout, hbuf, (ushort4*)hbuf16, (size_t)N * (NF / 4));
    } else {
      k_colstats<<<256, 256, 0, stream>>>(gout, N, stats + L * 256);
      k_bnres<<<1024, 256, 0, stream>>>(gout, stats + L * 256, hbuf, (ushort4*)hbuf16, N);
    }
  }

  k_pool<<<128, 256, 0, stream>>>(hbuf, batch, gpool, N);
  k_head<<<1, 1024, 0, stream>>>(gpool, fc_w, fc_b, cls_w, cls_b, out);
}